// Round 1
// baseline (653.975 us; speedup 1.0000x reference)
//
#include <hip/hip_runtime.h>
#include <stdint.h>

// Round 1: correct baseline. bf16 MFMA via v_mfma_f32_16x16x16_bf16 (layout-certain),
// 3-stage pipeline: GEMM1 (x@Wqkv -> qkv bf16, SCALE folded into Wq/bq),
// windowed attention (swapped-operand S^T = K*Q^T, in-register softmax, O^T = V^T*P^T),
// GEMM2 (attnout@Wm + bm -> fp32 out).

typedef __attribute__((ext_vector_type(4))) float f32x4;
typedef __attribute__((ext_vector_type(4))) short s16x4;
typedef __attribute__((ext_vector_type(8))) short s16x8;

#define DEVI static __device__ __forceinline__

DEVI unsigned short f2bf(float f) {
  union { float f; uint32_t u; } v; v.f = f;
  return (unsigned short)((v.u + 0x7FFFu + ((v.u >> 16) & 1u)) >> 16);
}

DEVI f32x4 zero4() { f32x4 z; z[0] = 0.f; z[1] = 0.f; z[2] = 0.f; z[3] = 0.f; return z; }

#if defined(__has_builtin)
#if __has_builtin(__builtin_amdgcn_mfma_f32_16x16x16bf16_1k)
#define MFMA_BUILTIN 1
#endif
#endif

DEVI f32x4 mfma16(s16x4 a, s16x4 b, f32x4 c) {
#ifdef MFMA_BUILTIN
  return __builtin_amdgcn_mfma_f32_16x16x16bf16_1k(a, b, c, 0, 0, 0);
#else
  asm volatile("v_mfma_f32_16x16x16_bf16 %0, %1, %2, %0" : "+v"(c) : "v"(a), "v"(b));
  return c;
#endif
}

// ---------------- prep kernels ----------------
__global__ void prep_wqkvT(const float* __restrict__ W, unsigned short* __restrict__ WT) {
  int t = blockIdx.x * 256 + threadIdx.x;
  if (t >= 1152 * 384) return;
  int n = t / 384, k = t - n * 384;
  float s = (n < 384) ? 0.17677669529663687f : 1.0f;  // HEAD_DIM^-0.5 folded into Wq
  WT[t] = f2bf(W[(size_t)k * 1152 + n] * s);
}

__global__ void prep_wmT(const float* __restrict__ W, unsigned short* __restrict__ WT) {
  int t = blockIdx.x * 256 + threadIdx.x;
  if (t >= 384 * 384) return;
  int n = t / 384, k = t - n * 384;
  WT[t] = f2bf(W[(size_t)k * 384 + n]);
}

__global__ void prep_bqkv(const float* __restrict__ b, float* __restrict__ bs) {
  int t = blockIdx.x * 256 + threadIdx.x;
  if (t >= 1152) return;
  bs[t] = b[t] * ((t < 384) ? 0.17677669529663687f : 1.0f);
}

// biasT[h][j][i] = bias[h][i][j] = rel_table[relidx(i,j)*12 + h]
__global__ void prep_bias(const float* __restrict__ rel, float* __restrict__ biasT) {
  int t = blockIdx.x * 256 + threadIdx.x;
  if (t >= 12 * 64 * 64) return;
  int h = t >> 12;
  int j = (t >> 6) & 63;
  int i = t & 63;
  int idx = ((i >> 3) - (j >> 3) + 7) * 15 + ((i & 7) - (j & 7) + 7);
  biasT[t] = rel[idx * 12 + h];
}

__global__ void fill_val(float* o, int n, float v) {
  int t = blockIdx.x * 256 + threadIdx.x;
  if (t < n) o[t] = v;
}

// ---------------- GEMM: C[M,N] = A[M,K] @ BT[N,K]^T + bias[N] ----------------
// blockIdx.x = n-tile (fast: N-tiles sharing an A panel run ~concurrently -> L3 reuse)
// blockIdx.y = m-tile. 128x128 tile, BK=64, 4 waves, each wave 64x64 (4x4 16x16 frags).
template <bool A_F32, bool OUT_F32>
__global__ __launch_bounds__(256) void gemm_k(const void* __restrict__ Av,
                                              const unsigned short* __restrict__ BT,
                                              const float* __restrict__ biasv,
                                              void* __restrict__ Cv, int N, int K) {
  constexpr int BM = 128, BN = 128, BK = 64, LDT = BK + 8;  // pad 8 -> stride 144B (16-aligned)
  __shared__ unsigned short As[BM * LDT];
  __shared__ unsigned short Bs[BN * LDT];
  const int n0 = blockIdx.x * BN;
  const int m0 = blockIdx.y * BM;
  const int tid = threadIdx.x;
  const int lane = tid & 63, wv = tid >> 6;
  const int wr = wv >> 1, wc = wv & 1;
  const int lg = lane >> 4, lr = lane & 15;
  const int sr = tid >> 1, sc = (tid & 1) * 32;  // staging: thread -> row sr, 32 cols

  f32x4 acc[4][4];
  for (int i = 0; i < 4; ++i) {
    for (int j = 0; j < 4; ++j) { acc[i][j] = zero4(); }
  }

  for (int k0 = 0; k0 < K; k0 += BK) {
    if constexpr (A_F32) {
      const float* ap = (const float*)Av + (size_t)(m0 + sr) * K + k0 + sc;
#pragma unroll
      for (int v = 0; v < 4; ++v) {
        f32x4 f0 = *(const f32x4*)(ap + v * 8);
        f32x4 f1 = *(const f32x4*)(ap + v * 8 + 4);
        s16x8 pk;
        pk[0] = (short)f2bf(f0[0]); pk[1] = (short)f2bf(f0[1]);
        pk[2] = (short)f2bf(f0[2]); pk[3] = (short)f2bf(f0[3]);
        pk[4] = (short)f2bf(f1[0]); pk[5] = (short)f2bf(f1[1]);
        pk[6] = (short)f2bf(f1[2]); pk[7] = (short)f2bf(f1[3]);
        *(s16x8*)&As[sr * LDT + sc + v * 8] = pk;
      }
    } else {
      const unsigned short* ap = (const unsigned short*)Av + (size_t)(m0 + sr) * K + k0 + sc;
#pragma unroll
      for (int v = 0; v < 4; ++v) {
        *(s16x8*)&As[sr * LDT + sc + v * 8] = *(const s16x8*)(ap + v * 8);
      }
    }
    {
      const unsigned short* bp = BT + (size_t)(n0 + sr) * K + k0 + sc;
#pragma unroll
      for (int v = 0; v < 4; ++v) {
        *(s16x8*)&Bs[sr * LDT + sc + v * 8] = *(const s16x8*)(bp + v * 8);
      }
    }
    __syncthreads();
#pragma unroll
    for (int kk = 0; kk < BK; kk += 16) {
      s16x4 af[4], bfr[4];
#pragma unroll
      for (int t = 0; t < 4; ++t) {
        af[t] = *(const s16x4*)&As[(wr * 64 + t * 16 + lr) * LDT + kk + 4 * lg];
      }
#pragma unroll
      for (int t = 0; t < 4; ++t) {
        bfr[t] = *(const s16x4*)&Bs[(wc * 64 + t * 16 + lr) * LDT + kk + 4 * lg];
      }
#pragma unroll
      for (int it = 0; it < 4; ++it) {
#pragma unroll
        for (int jt = 0; jt < 4; ++jt) {
          acc[it][jt] = mfma16(af[it], bfr[jt], acc[it][jt]);
        }
      }
    }
    __syncthreads();
  }

  // C/D layout: row = 4*lg + e (+16*it), col = lr (+16*jt)
  const int crow = m0 + wr * 64 + lg * 4;
  const int ccol = n0 + wc * 64 + lr;
#pragma unroll
  for (int it = 0; it < 4; ++it) {
#pragma unroll
    for (int jt = 0; jt < 4; ++jt) {
      const int col = ccol + jt * 16;
      const float bv = biasv[col];
#pragma unroll
      for (int e = 0; e < 4; ++e) {
        const float val = acc[it][jt][e] + bv;
        const size_t idx = (size_t)(crow + it * 16 + e) * N + col;
        if constexpr (OUT_F32) {
          ((float*)Cv)[idx] = val;
        } else {
          ((unsigned short*)Cv)[idx] = f2bf(val);
        }
      }
    }
  }
}

// ---------------- windowed attention: one wave per (window, head) ----------------
// S^T = K * Q^T (so softmax over j = rows of S^T is local+2 shfl), then O^T = V^T * P^T,
// where P^T fragments come straight out of the softmax'd accumulator (no lane exchange).
__global__ __launch_bounds__(256) void attn_k(const unsigned short* __restrict__ qkv,
                                              const float* __restrict__ biasT,
                                              unsigned short* __restrict__ attnout) {
  const int lane = threadIdx.x & 63;
  const int wv = threadIdx.x >> 6;
  const int hg = blockIdx.x * 4 + wv;  // [0, 24576)
  const int bg = hg / 12;
  const int h = hg - bg * 12;
  const int lg = lane >> 4, lr = lane & 15;

  const unsigned short* base = qkv + (size_t)bg * 64 * 1152;
  const int colq = h * 32, colk = 384 + h * 32, colv = 768 + h * 32;

  // A-frags of K (rows j), B-frags of Q^T (cols i); k-dim = DH = 32 -> 2 ksteps
  s16x4 ka[4][2], qb[2][4];
#pragma unroll
  for (int jt = 0; jt < 4; ++jt) {
#pragma unroll
    for (int kt = 0; kt < 2; ++kt) {
      ka[jt][kt] = *(const s16x4*)&base[(size_t)(jt * 16 + lr) * 1152 + colk + kt * 16 + 4 * lg];
    }
  }
#pragma unroll
  for (int it = 0; it < 4; ++it) {
#pragma unroll
    for (int kt = 0; kt < 2; ++kt) {
      qb[kt][it] = *(const s16x4*)&base[(size_t)(it * 16 + lr) * 1152 + colq + kt * 16 + 4 * lg];
    }
  }

  f32x4 c[4][4];
  for (int a = 0; a < 4; ++a) {
    for (int b2 = 0; b2 < 4; ++b2) { c[a][b2] = zero4(); }
  }

#pragma unroll
  for (int kt = 0; kt < 2; ++kt) {
#pragma unroll
    for (int jt = 0; jt < 4; ++jt) {
#pragma unroll
      for (int it = 0; it < 4; ++it) {
        c[jt][it] = mfma16(ka[jt][kt], qb[kt][it], c[jt][it]);
      }
    }
  }

  // bias: S^T[j][i] += bias[h][i][j]; j = jt*16 + lg*4 + e, i = it*16 + lr
#pragma unroll
  for (int jt = 0; jt < 4; ++jt) {
#pragma unroll
    for (int it = 0; it < 4; ++it) {
      const float* bp = biasT + h * 4096 + (jt * 16 + lg * 4) * 64 + it * 16 + lr;
#pragma unroll
      for (int e = 0; e < 4; ++e) { c[jt][it][e] += bp[e * 64]; }
    }
  }

  // softmax over j for each column i; lanes sharing i: {l, l^16, l^32, l^48}
  s16x4 pb[4][4];
#pragma unroll
  for (int it = 0; it < 4; ++it) {
    float m = -3.0e38f;
#pragma unroll
    for (int jt = 0; jt < 4; ++jt) {
#pragma unroll
      for (int e = 0; e < 4; ++e) { m = fmaxf(m, c[jt][it][e]); }
    }
    m = fmaxf(m, __shfl_xor(m, 16));
    m = fmaxf(m, __shfl_xor(m, 32));
    float s = 0.f;
#pragma unroll
    for (int jt = 0; jt < 4; ++jt) {
#pragma unroll
      for (int e = 0; e < 4; ++e) {
        float p = __expf(c[jt][it][e] - m);
        c[jt][it][e] = p;
        s += p;
      }
    }
    s += __shfl_xor(s, 16);
    s += __shfl_xor(s, 32);
    const float inv = 1.f / s;
#pragma unroll
    for (int jt = 0; jt < 4; ++jt) {
      s16x4 pk;
#pragma unroll
      for (int e = 0; e < 4; ++e) { pk[e] = (short)f2bf(c[jt][it][e] * inv); }
      pb[jt][it] = pk;
    }
  }

  // O^T = V^T * P^T ; A-frag of V^T: lane holds v[jt*16+4*lg+e][dt*16+lr]
  f32x4 o[2][4];
  for (int a = 0; a < 2; ++a) {
    for (int b2 = 0; b2 < 4; ++b2) { o[a][b2] = zero4(); }
  }

#pragma unroll
  for (int jt = 0; jt < 4; ++jt) {
    s16x4 va[2];
#pragma unroll
    for (int dt = 0; dt < 2; ++dt) {
      const size_t rbase = (size_t)(jt * 16 + lg * 4) * 1152 + colv + dt * 16 + lr;
      s16x4 t;
      t[0] = (short)base[rbase];
      t[1] = (short)base[rbase + 1152];
      t[2] = (short)base[rbase + 2304];
      t[3] = (short)base[rbase + 3456];
      va[dt] = t;
    }
#pragma unroll
    for (int dt = 0; dt < 2; ++dt) {
#pragma unroll
      for (int it = 0; it < 4; ++it) {
        o[dt][it] = mfma16(va[dt], pb[jt][it], o[dt][it]);
      }
    }
  }

  // O^T[d][i]: d = dt*16 + 4*lg + e, i = it*16 + lr -> attnout[i][h*32+d], 4 consecutive d
  unsigned short* ob = attnout + (size_t)bg * 64 * 384;
#pragma unroll
  for (int dt = 0; dt < 2; ++dt) {
#pragma unroll
    for (int it = 0; it < 4; ++it) {
      s16x4 pk;
#pragma unroll
      for (int e = 0; e < 4; ++e) { pk[e] = (short)f2bf(o[dt][it][e]); }
      const int i = it * 16 + lr;
      const int d = dt * 16 + lg * 4;
      *(s16x4*)&ob[(size_t)i * 384 + h * 32 + d] = pk;
    }
  }
}

extern "C" void kernel_launch(void* const* d_in, const int* in_sizes, int n_in,
                              void* d_out, int out_size, void* d_ws, size_t ws_size,
                              hipStream_t stream) {
  const float* x = (const float*)d_in[0];
  const float* Wqkv = (const float*)d_in[1];
  const float* bqkv = (const float*)d_in[2];
  const float* Wm = (const float*)d_in[3];
  const float* bm = (const float*)d_in[4];
  const float* rel = (const float*)d_in[5];

  const size_t M = 131072;  // B*G*P = 32*64*64
  char* ws = (char*)d_ws;
  size_t off = 0;
  unsigned short* qkv = (unsigned short*)(ws + off);   off += M * 1152 * 2;   // 302 MB
  unsigned short* attn = (unsigned short*)(ws + off);  off += M * 384 * 2;    // 100 MB
  unsigned short* WqkvT = (unsigned short*)(ws + off); off += 1152 * 384 * 2;
  unsigned short* WmT = (unsigned short*)(ws + off);   off += 384 * 384 * 2;
  float* biasT = (float*)(ws + off);                   off += 12 * 64 * 64 * 4;
  float* bqkvs = (float*)(ws + off);                   off += 1152 * 4;

  if (ws_size < off) {
    // diagnosable sentinel: absmax ~12345 means "workspace too small"
    fill_val<<<(out_size + 255) / 256, 256, 0, stream>>>((float*)d_out, out_size, 12345.0f);
    return;
  }

  prep_wqkvT<<<(1152 * 384 + 255) / 256, 256, 0, stream>>>(Wqkv, WqkvT);
  prep_wmT<<<(384 * 384 + 255) / 256, 256, 0, stream>>>(Wm, WmT);
  prep_bqkv<<<5, 256, 0, stream>>>(bqkv, bqkvs);
  prep_bias<<<(12 * 64 * 64 + 255) / 256, 256, 0, stream>>>(rel, biasT);

  // GEMM1: qkv[M,1152] = x[M,384] @ WqkvT^T + bqkvs (bf16 out, q pre-scaled)
  gemm_k<true, false><<<dim3(9, 1024), 256, 0, stream>>>(x, WqkvT, bqkvs, qkv, 1152, 384);
  // attention: one wave per (window, head)
  attn_k<<<6144, 256, 0, stream>>>(qkv, biasT, attn);
  // GEMM2: out[M,384] = attn[M,384] @ WmT^T + bm (fp32 out)
  gemm_k<false, true><<<dim3(3, 1024), 256, 0, stream>>>(attn, WmT, bm, d_out, 384, 384);
}

// Round 2
// 608.705 us; speedup vs baseline: 1.0744x; 1.0744x over previous
//
#include <hip/hip_runtime.h>
#include <stdint.h>

// Round 2: (a) x pre-converted to bf16; (b) GEMM1 rebuilt in the m97 pattern:
// global_load_lds(16B) staging, linear 128x64 LDS tiles, mfma_f32_16x16x32_bf16;
// (c) attention fused with GEMM2 (attnout lives in LDS, never touches HBM).

typedef __attribute__((ext_vector_type(4))) float f32x4;
typedef __attribute__((ext_vector_type(4))) short s16x4;
typedef __attribute__((ext_vector_type(8))) short s16x8;

#define DEVI static __device__ __forceinline__

DEVI unsigned short f2bf(float f) {
  union { float f; uint32_t u; } v; v.f = f;
  return (unsigned short)((v.u + 0x7FFFu + ((v.u >> 16) & 1u)) >> 16);
}

DEVI f32x4 zero4() { f32x4 z; z[0] = 0.f; z[1] = 0.f; z[2] = 0.f; z[3] = 0.f; return z; }

#if defined(__has_builtin)
#if __has_builtin(__builtin_amdgcn_mfma_f32_16x16x16bf16_1k)
#define MFMA16_BUILTIN 1
#endif
#if __has_builtin(__builtin_amdgcn_global_load_lds)
#define HAS_GLLDS 1
#endif
#endif

DEVI f32x4 mfma16(s16x4 a, s16x4 b, f32x4 c) {
#ifdef MFMA16_BUILTIN
  return __builtin_amdgcn_mfma_f32_16x16x16bf16_1k(a, b, c, 0, 0, 0);
#else
  asm volatile("v_mfma_f32_16x16x16_bf16 %0, %1, %2, %0" : "+v"(c) : "v"(a), "v"(b));
  return c;
#endif
}

DEVI f32x4 mfma32(s16x8 a, s16x8 b, f32x4 c) {
  return __builtin_amdgcn_mfma_f32_16x16x32_bf16(a, b, c, 0, 0, 0);
}

// Copy 1 KiB per wave: lane l copies 16B  g_lane -> lds_base + l*16.
// g_lane is per-lane; lds_base must be wave-uniform (HW adds lane*16).
DEVI void stage1k(const unsigned short* g_lane, unsigned short* lds_base, int lane) {
#ifdef HAS_GLLDS
  __builtin_amdgcn_global_load_lds(
      (const __attribute__((address_space(1))) unsigned int*)g_lane,
      (__attribute__((address_space(3))) unsigned int*)lds_base, 16, 0, 0);
#else
  *(s16x8*)(lds_base + lane * 8) = *(const s16x8*)g_lane;
#endif
}

// ---------------- prep kernels ----------------
__global__ void prep_wqkvT(const float* __restrict__ W, unsigned short* __restrict__ WT) {
  int t = blockIdx.x * 256 + threadIdx.x;
  if (t >= 1152 * 384) return;
  int n = t / 384, k = t - n * 384;
  float s = (n < 384) ? 0.17677669529663687f : 1.0f;  // HEAD_DIM^-0.5 folded into Wq
  WT[t] = f2bf(W[(size_t)k * 1152 + n] * s);
}

__global__ void prep_wmT(const float* __restrict__ W, unsigned short* __restrict__ WT) {
  int t = blockIdx.x * 256 + threadIdx.x;
  if (t >= 384 * 384) return;
  int n = t / 384, k = t - n * 384;
  WT[t] = f2bf(W[(size_t)k * 384 + n]);
}

__global__ void prep_bqkv(const float* __restrict__ b, float* __restrict__ bs) {
  int t = blockIdx.x * 256 + threadIdx.x;
  if (t >= 1152) return;
  bs[t] = b[t] * ((t < 384) ? 0.17677669529663687f : 1.0f);
}

// biasT[h][j][i] = bias[h][i][j] = rel_table[relidx(i,j)*12 + h]
__global__ void prep_bias(const float* __restrict__ rel, float* __restrict__ biasT) {
  int t = blockIdx.x * 256 + threadIdx.x;
  if (t >= 12 * 64 * 64) return;
  int h = t >> 12;
  int j = (t >> 6) & 63;
  int i = t & 63;
  int idx = ((i >> 3) - (j >> 3) + 7) * 15 + ((i & 7) - (j & 7) + 7);
  biasT[t] = rel[idx * 12 + h];
}

__global__ void fill_val(float* o, int n, float v) {
  int t = blockIdx.x * 256 + threadIdx.x;
  if (t < n) o[t] = v;
}

// ---------------- x fp32 -> bf16 ----------------
__global__ __launch_bounds__(256) void conv_bf16(const float* __restrict__ x,
                                                 unsigned short* __restrict__ xb) {
  const size_t nchunk = 131072UL * 384 / 8;
  const size_t stride = (size_t)gridDim.x * blockDim.x;
  for (size_t i = (size_t)blockIdx.x * blockDim.x + threadIdx.x; i < nchunk; i += stride) {
    f32x4 a = *(const f32x4*)(x + i * 8);
    f32x4 b = *(const f32x4*)(x + i * 8 + 4);
    s16x8 p;
    p[0] = (short)f2bf(a[0]); p[1] = (short)f2bf(a[1]);
    p[2] = (short)f2bf(a[2]); p[3] = (short)f2bf(a[3]);
    p[4] = (short)f2bf(b[0]); p[5] = (short)f2bf(b[1]);
    p[6] = (short)f2bf(b[2]); p[7] = (short)f2bf(b[3]);
    *(s16x8*)(xb + i * 8) = p;
  }
}

// ---------------- GEMM1: qkv[M,1152] = x_bf16[M,384] @ WqkvT^T + bias ----------------
// m97 pattern: 128x128 tile, BK=64, linear LDS [128][64], global_load_lds 16B,
// mfma_f32_16x16x32_bf16, 4 waves (2x2), 2 barriers per k-iter.
__global__ __launch_bounds__(256) void gemm1_k(const unsigned short* __restrict__ A,
                                               const unsigned short* __restrict__ BT,
                                               const float* __restrict__ bias,
                                               unsigned short* __restrict__ C) {
  constexpr int K = 384, N = 1152;
  __shared__ unsigned short As[128 * 64];
  __shared__ unsigned short Bs[128 * 64];
  const int tid = threadIdx.x;
  const int lane = tid & 63, wv = tid >> 6;
  const int n0 = blockIdx.x * 128, m0 = blockIdx.y * 128;
  const int wr = wv >> 1, wc = wv & 1;
  const int lg = lane >> 4, lr = lane & 15;

  // staging: wave wv covers rows [wv*32, wv*32+32), 4 calls of 8 rows (1 KiB) each
  const int srow = wv * 32 + (lane >> 3);
  const int scol = (lane & 7) * 8;
  const unsigned short* Ag = A + (size_t)(m0 + srow) * K + scol;
  const unsigned short* Bg = BT + (size_t)(n0 + srow) * K + scol;

  f32x4 acc[4][4];
#pragma unroll
  for (int i = 0; i < 4; ++i)
#pragma unroll
    for (int j = 0; j < 4; ++j) acc[i][j] = zero4();

  for (int k0 = 0; k0 < K; k0 += 64) {
#pragma unroll
    for (int c = 0; c < 4; ++c)
      stage1k(Ag + (size_t)(c * 8) * K + k0, &As[(wv * 32 + c * 8) * 64], lane);
#pragma unroll
    for (int c = 0; c < 4; ++c)
      stage1k(Bg + (size_t)(c * 8) * K + k0, &Bs[(wv * 32 + c * 8) * 64], lane);
    __syncthreads();
#pragma unroll
    for (int kk = 0; kk < 64; kk += 32) {
      s16x8 af[4], bf[4];
#pragma unroll
      for (int mt = 0; mt < 4; ++mt)
        af[mt] = *(const s16x8*)&As[(wr * 64 + 16 * mt + lr) * 64 + kk + 8 * lg];
#pragma unroll
      for (int nt = 0; nt < 4; ++nt)
        bf[nt] = *(const s16x8*)&Bs[(wc * 64 + 16 * nt + lr) * 64 + kk + 8 * lg];
#pragma unroll
      for (int mt = 0; mt < 4; ++mt)
#pragma unroll
        for (int nt = 0; nt < 4; ++nt)
          acc[mt][nt] = mfma32(af[mt], bf[nt], acc[mt][nt]);
    }
    __syncthreads();
  }

  const int crow = m0 + wr * 64 + 4 * lg;
  const int ccol = n0 + wc * 64 + lr;
#pragma unroll
  for (int mt = 0; mt < 4; ++mt)
#pragma unroll
    for (int nt = 0; nt < 4; ++nt) {
      const int col = ccol + 16 * nt;
      const float bv = bias[col];
#pragma unroll
      for (int e = 0; e < 4; ++e)
        C[(size_t)(crow + 16 * mt + e) * N + col] = f2bf(acc[mt][nt][e] + bv);
    }
}

// ---------------- fused attention + GEMM2, one block per window ----------------
// Phase 1: 4 waves x 3 heads: S^T = K*Q^T + bias, softmax, O^T = V^T*P^T,
//          O -> LDS attnout[64][392] bf16.
// Phase 2: out[64,384] = attnout @ Wm + bm, wave w owns 96 output cols.
__global__ __launch_bounds__(256) void attn_gemm2_k(const unsigned short* __restrict__ qkv,
                                                    const float* __restrict__ biasT,
                                                    const unsigned short* __restrict__ WmT,
                                                    const float* __restrict__ bm,
                                                    float* __restrict__ out) {
  __shared__ unsigned short att_s[64 * 392];
  const int lane = threadIdx.x & 63;
  const int wv = threadIdx.x >> 6;
  const int bg = blockIdx.x;  // window index [0, 2048)
  const int lg = lane >> 4, lr = lane & 15;
  const unsigned short* base = qkv + (size_t)bg * 64 * 1152;

#pragma unroll 1
  for (int hi = 0; hi < 3; ++hi) {
    const int h = wv * 3 + hi;
    const int colq = h * 32, colk = 384 + h * 32, colv = 768 + h * 32;

    s16x4 ka[4][2], qb[2][4];
#pragma unroll
    for (int jt = 0; jt < 4; ++jt)
#pragma unroll
      for (int kt = 0; kt < 2; ++kt)
        ka[jt][kt] = *(const s16x4*)&base[(size_t)(jt * 16 + lr) * 1152 + colk + kt * 16 + 4 * lg];
#pragma unroll
    for (int it = 0; it < 4; ++it)
#pragma unroll
      for (int kt = 0; kt < 2; ++kt)
        qb[kt][it] = *(const s16x4*)&base[(size_t)(it * 16 + lr) * 1152 + colq + kt * 16 + 4 * lg];

    f32x4 c[4][4];
#pragma unroll
    for (int a = 0; a < 4; ++a)
#pragma unroll
      for (int b2 = 0; b2 < 4; ++b2) c[a][b2] = zero4();

#pragma unroll
    for (int kt = 0; kt < 2; ++kt)
#pragma unroll
      for (int jt = 0; jt < 4; ++jt)
#pragma unroll
        for (int it = 0; it < 4; ++it)
          c[jt][it] = mfma16(ka[jt][kt], qb[kt][it], c[jt][it]);

    // bias: S^T[j][i] += bias[h][i][j]; j = jt*16+lg*4+e, i = it*16+lr
#pragma unroll
    for (int jt = 0; jt < 4; ++jt)
#pragma unroll
      for (int it = 0; it < 4; ++it) {
        const float* bp = biasT + h * 4096 + (jt * 16 + lg * 4) * 64 + it * 16 + lr;
#pragma unroll
        for (int e = 0; e < 4; ++e) c[jt][it][e] += bp[e * 64];
      }

    // softmax over j per column i; lanes sharing i: {l, l^16, l^32, l^48}
    s16x4 pb[4][4];
#pragma unroll
    for (int it = 0; it < 4; ++it) {
      float m = -3.0e38f;
#pragma unroll
      for (int jt = 0; jt < 4; ++jt)
#pragma unroll
        for (int e = 0; e < 4; ++e) m = fmaxf(m, c[jt][it][e]);
      m = fmaxf(m, __shfl_xor(m, 16));
      m = fmaxf(m, __shfl_xor(m, 32));
      float s = 0.f;
#pragma unroll
      for (int jt = 0; jt < 4; ++jt)
#pragma unroll
        for (int e = 0; e < 4; ++e) {
          float p = __expf(c[jt][it][e] - m);
          c[jt][it][e] = p;
          s += p;
        }
      s += __shfl_xor(s, 16);
      s += __shfl_xor(s, 32);
      const float inv = 1.f / s;
#pragma unroll
      for (int jt = 0; jt < 4; ++jt) {
        s16x4 pk;
#pragma unroll
        for (int e = 0; e < 4; ++e) pk[e] = (short)f2bf(c[jt][it][e] * inv);
        pb[jt][it] = pk;
      }
    }

    // O^T = V^T * P^T
    f32x4 o[2][4];
#pragma unroll
    for (int a = 0; a < 2; ++a)
#pragma unroll
      for (int b2 = 0; b2 < 4; ++b2) o[a][b2] = zero4();

#pragma unroll
    for (int jt = 0; jt < 4; ++jt) {
      s16x4 va[2];
#pragma unroll
      for (int dt = 0; dt < 2; ++dt) {
        const size_t rbase = (size_t)(jt * 16 + lg * 4) * 1152 + colv + dt * 16 + lr;
        s16x4 t;
        t[0] = (short)base[rbase];
        t[1] = (short)base[rbase + 1152];
        t[2] = (short)base[rbase + 2304];
        t[3] = (short)base[rbase + 3456];
        va[dt] = t;
      }
#pragma unroll
      for (int dt = 0; dt < 2; ++dt)
#pragma unroll
        for (int it = 0; it < 4; ++it)
          o[dt][it] = mfma16(va[dt], pb[jt][it], o[dt][it]);
    }

    // O^T[d][i]: d = dt*16+4lg+e, i = it*16+lr  ->  att_s[i][h*32+d]
#pragma unroll
    for (int dt = 0; dt < 2; ++dt)
#pragma unroll
      for (int it = 0; it < 4; ++it) {
        s16x4 pk;
#pragma unroll
        for (int e = 0; e < 4; ++e) pk[e] = (short)f2bf(o[dt][it][e]);
        *(s16x4*)&att_s[(it * 16 + lr) * 392 + h * 32 + dt * 16 + 4 * lg] = pk;
      }
  }

  __syncthreads();

  // Phase 2: GEMM2. wave wv -> output cols [wv*96, wv*96+96)
  f32x4 acc[4][6];
#pragma unroll
  for (int mt = 0; mt < 4; ++mt)
#pragma unroll
    for (int nt = 0; nt < 6; ++nt) acc[mt][nt] = zero4();

  const int n0w = wv * 96;
#pragma unroll 2
  for (int ks = 0; ks < 24; ++ks) {
    s16x4 af[4], bfr[6];
#pragma unroll
    for (int mt = 0; mt < 4; ++mt)
      af[mt] = *(const s16x4*)&att_s[(16 * mt + lr) * 392 + ks * 16 + 4 * lg];
#pragma unroll
    for (int nt = 0; nt < 6; ++nt)
      bfr[nt] = *(const s16x4*)&WmT[(size_t)(n0w + 16 * nt + lr) * 384 + ks * 16 + 4 * lg];
#pragma unroll
    for (int mt = 0; mt < 4; ++mt)
#pragma unroll
      for (int nt = 0; nt < 6; ++nt)
        acc[mt][nt] = mfma16(af[mt], bfr[nt], acc[mt][nt]);
  }

  float* ob = out + (size_t)bg * 64 * 384;
#pragma unroll
  for (int mt = 0; mt < 4; ++mt)
#pragma unroll
    for (int nt = 0; nt < 6; ++nt) {
      const int col = n0w + 16 * nt + lr;
      const float bv = bm[col];
#pragma unroll
      for (int e = 0; e < 4; ++e)
        ob[(size_t)(16 * mt + 4 * lg + e) * 384 + col] = acc[mt][nt][e] + bv;
    }
}

extern "C" void kernel_launch(void* const* d_in, const int* in_sizes, int n_in,
                              void* d_out, int out_size, void* d_ws, size_t ws_size,
                              hipStream_t stream) {
  const float* x = (const float*)d_in[0];
  const float* Wqkv = (const float*)d_in[1];
  const float* bqkv = (const float*)d_in[2];
  const float* Wm = (const float*)d_in[3];
  const float* bm = (const float*)d_in[4];
  const float* rel = (const float*)d_in[5];

  const size_t M = 131072;  // B*G*P
  char* ws = (char*)d_ws;
  size_t off = 0;
  unsigned short* qkv = (unsigned short*)(ws + off);   off += M * 1152 * 2;  // 302 MB
  unsigned short* xb = (unsigned short*)(ws + off);    off += M * 384 * 2;   // 100 MB
  unsigned short* WqkvT = (unsigned short*)(ws + off); off += 1152 * 384 * 2;
  unsigned short* WmT = (unsigned short*)(ws + off);   off += 384 * 384 * 2;
  float* biasT = (float*)(ws + off);                   off += 12 * 64 * 64 * 4;
  float* bqkvs = (float*)(ws + off);                   off += 1152 * 4;

  if (ws_size < off) {
    fill_val<<<(out_size + 255) / 256, 256, 0, stream>>>((float*)d_out, out_size, 12345.0f);
    return;
  }

  prep_wqkvT<<<(1152 * 384 + 255) / 256, 256, 0, stream>>>(Wqkv, WqkvT);
  prep_wmT<<<(384 * 384 + 255) / 256, 256, 0, stream>>>(Wm, WmT);
  prep_bqkv<<<5, 256, 0, stream>>>(bqkv, bqkvs);
  prep_bias<<<(12 * 64 * 64 + 255) / 256, 256, 0, stream>>>(rel, biasT);
  conv_bf16<<<2048, 256, 0, stream>>>(x, xb);

  gemm1_k<<<dim3(9, 1024), 256, 0, stream>>>(xb, WqkvT, bqkvs, qkv);
  attn_gemm2_k<<<2048, 256, 0, stream>>>(qkv, biasT, WmT, bm, (float*)d_out);
}